// Round 1
// 193.570 us; speedup vs baseline: 1.0086x; 1.0086x over previous
//
#include <hip/hip_runtime.h>

#define BB 8
#define NN 8192
#define SS 2048
#define CC 64
#define NS 32
#define COUT 67   // 3 xyz + 64 feature channels
#define QT 8      // queries per gather block
#define P0 19     // planes in quad 0 (3 xyz + 16 feat); quads 1..3 have 16

// ---------------- Kernel A: ball-query scan, float4-vectorized loads --------
// Lane owns 4 consecutive points: j = j0 + 4*lane + u. 3x dwordx4 per chunk
// (vs 12 scalar dwords), each a coalesced 1KB wave fetch. Hit ordering is
// lane-major: pos = total + sum_u popc(M[u] & lt) + (#own hits with u'<u).
__global__ __launch_bounds__(256) void scan_kernel(
    const float* __restrict__ xyz,      // (B, N, 3)
    const float* __restrict__ new_xyz,  // (B, S, 3)
    int* __restrict__ idx_ws)           // (B*S, NS)
{
#pragma clang fp contract(off)
    const int wave = threadIdx.x >> 6;
    const int lane = threadIdx.x & 63;
    const int qid  = blockIdx.x * 4 + wave;
    const int b = qid >> 11;
    const int s = qid & 2047;

    const float R2 = 0.04f;   // f32 nearest of 0.2*0.2; strict '<' matches ref

    const float* ctr = new_xyz + ((size_t)b * SS + s) * 3;
    const float cx = ctr[0], cy = ctr[1], cz = ctr[2];
    const float* xb = xyz + (size_t)b * NN * 3;

    int* myidx = idx_ws + (size_t)qid * NS;
    const unsigned long long lt = (1ull << lane) - 1ull;

    int total = 0;
    int firstIdx = -1;
    for (int j0 = 0; j0 < NN && total < NS; j0 += 256) {
        // 48B-aligned: (j0 + 4*lane)*12 bytes is a multiple of 48
        const float4* p4 = (const float4*)(xb + (size_t)(j0 + (lane << 2)) * 3);
        const float4 A  = p4[0];   // x0 y0 z0 x1
        const float4 Bv = p4[1];   // y1 z1 x2 y2
        const float4 Cv = p4[2];   // z2 x3 y3 z3
        float d2v[4];
        {
            const float dx = A.x - cx, dy = A.y - cy, dz = A.z - cz;
            float d2 = dx * dx; d2 = d2 + dy * dy; d2 = d2 + dz * dz;
            d2v[0] = d2;
        }
        {
            const float dx = A.w - cx, dy = Bv.x - cy, dz = Bv.y - cz;
            float d2 = dx * dx; d2 = d2 + dy * dy; d2 = d2 + dz * dz;
            d2v[1] = d2;
        }
        {
            const float dx = Bv.z - cx, dy = Bv.w - cy, dz = Cv.x - cz;
            float d2 = dx * dx; d2 = d2 + dy * dy; d2 = d2 + dz * dz;
            d2v[2] = d2;
        }
        {
            const float dx = Cv.y - cx, dy = Cv.z - cy, dz = Cv.w - cz;
            float d2 = dx * dx; d2 = d2 + dy * dy; d2 = d2 + dz * dz;
            d2v[3] = d2;
        }

        unsigned long long M[4];
#pragma unroll
        for (int u = 0; u < 4; ++u) M[u] = __ballot(d2v[u] < R2);

        if (firstIdx < 0) {
            int fmin = 0x7fffffff;
#pragma unroll
            for (int u = 0; u < 4; ++u)
                if (M[u] != 0ull) {
                    const int j = j0 + (__builtin_ctzll(M[u]) << 2) + u;
                    fmin = (j < fmin) ? j : fmin;
                }
            if (fmin != 0x7fffffff) firstIdx = fmin;
        }

        int below = 0;   // hits in earlier lanes (any u) -> smaller j
#pragma unroll
        for (int u = 0; u < 4; ++u) below += (int)__popcll(M[u] & lt);

        int own = 0;     // own hits with smaller u -> smaller j
#pragma unroll
        for (int u = 0; u < 4; ++u) {
            if (d2v[u] < R2) {
                const int pos = total + below + own;
                if (pos < NS) myidx[pos] = j0 + (lane << 2) + u;
                ++own;
            }
        }
#pragma unroll
        for (int u = 0; u < 4; ++u) total += (int)__popcll(M[u]);
    }
    if (total < NS) {
        const int fill = (total > 0) ? firstIdx : 0;
        if (lane >= total && lane < NS) myidx[lane] = fill;
    }
}

// ---------------- Kernel B: gather, quarter-channel split for occupancy -----
// 20 KB LDS/block (19 planes + idx) -> 8 blocks/CU (was 4 at 36.8 KB), 2x the
// wave cover for scattered L2-latency reads. Writes stay 1KB-contiguous per
// wave-store. quad 0: xyz + feat[0:16); quad y>=1: feat[16y : 16y+16).
__global__ __launch_bounds__(256) void gather_kernel(
    const float* __restrict__ xyz,      // (B, N, 3)
    const float* __restrict__ new_xyz,  // (B, S, 3)
    const float* __restrict__ feat,     // (B, N, C)
    const int* __restrict__ idx_ws,     // (B*S, NS)
    float* __restrict__ out)            // (B, 67, S, NS)
{
#pragma clang fp contract(off)
    __shared__ float tile[P0 * QT * NS];    // 19 * 256 floats = 19 KB
    __shared__ int idx_sh[QT * NS];         // 1 KB

    const int t     = threadIdx.x;          // = q*32 + k
    const int sTile = blockIdx.x;           // 0..255
    const int quad  = blockIdx.y;           // 0..3
    const int b     = blockIdx.z;           // 0..7

    const int s0 = sTile * QT;
    const int qbase = (b << 11) + s0;

    idx_sh[t] = idx_ws[(size_t)qbase * NS + t];
    __syncthreads();

    const int q = t >> 5;
    const int row = idx_sh[t];

    // ---- read phase: fill LDS tile [plane][q*32+k] ----
    const float* frow = feat + ((size_t)b * NN + row) * CC + quad * 16;
    const int pb = (quad == 0) ? 3 : 0;
    if (quad == 0) {
        const float* ctr = new_xyz + ((size_t)b * SS + s0 + q) * 3;
        const float* p   = xyz + ((size_t)b * NN + row) * 3;
        tile[0 * 256 + t] = p[0] - ctr[0];
        tile[1 * 256 + t] = p[1] - ctr[1];
        tile[2 * 256 + t] = p[2] - ctr[2];
    }
#pragma unroll
    for (int i = 0; i < 4; ++i) {
        const float4 f = *(const float4*)(frow + i * 4);
        tile[(pb + i * 4 + 0) * 256 + t] = f.x;
        tile[(pb + i * 4 + 1) * 256 + t] = f.y;
        tile[(pb + i * 4 + 2) * 256 + t] = f.z;
        tile[(pb + i * 4 + 3) * 256 + t] = f.w;
    }
    __syncthreads();

    // ---- write phase: one 1KB-contiguous wave-store per plane ----
    const int P     = (quad == 0) ? P0 : 16;        // planes this block owns
    const int cbase = (quad == 0) ? 0 : (3 + quad * 16);  // global channel base
    const int wv = t >> 6;
    const int ln = t & 63;
    const size_t plane = (size_t)SS * NS;
    float* ob = out + (((size_t)b * COUT + cbase) * SS + s0) * NS;
#pragma unroll
    for (int i = 0; i < 5; ++i) {
        const int p = i * 4 + wv;
        if (p < P) {
            const float4 v = *(const float4*)(tile + p * 256 + ln * 4);
            *(float4*)(ob + (size_t)p * plane + ln * 4) = v;
        }
    }
}

extern "C" void kernel_launch(void* const* d_in, const int* in_sizes, int n_in,
                              void* d_out, int out_size, void* d_ws, size_t ws_size,
                              hipStream_t stream) {
    const float* xyz     = (const float*)d_in[0];
    const float* new_xyz = (const float*)d_in[1];
    const float* feat    = (const float*)d_in[2];
    float* out = (float*)d_out;
    int* idx_ws = (int*)d_ws;   // B*S*NS ints = 2 MB

    scan_kernel<<<dim3((BB * SS) / 4), dim3(256), 0, stream>>>(xyz, new_xyz, idx_ws);
    gather_kernel<<<dim3(SS / QT, 4, BB), dim3(256), 0, stream>>>(xyz, new_xyz, feat, idx_ws, out);
}